// Round 13
// baseline (280.883 us; speedup 1.0000x reference)
//
#include <hip/hip_runtime.h>

#define N_NODES 50000
#define N_EDGES 800000
#define NBUCK   98            // buckets of 512 nodes (dst >> 9)
#define EPB     2048          // edges per scatter block
#define NSB     391           // scatter blocks = ceil(800000/2048)
#define BCAP    64            // per-(block,bucket) strip capacity (mean ~21)
#define CAPB    12288         // per-bucket e_src capacity (~8163 mean)

typedef __attribute__((ext_vector_type(8))) short short8;
typedef __attribute__((ext_vector_type(4))) float floatx4;

__device__ __forceinline__ float b2f(unsigned short u) {
    union { unsigned int i; float f; } v;
    v.i = ((unsigned int)u) << 16;
    return v.f;
}
__device__ __forceinline__ float ubits(unsigned int b) {
    union { unsigned int i; float f; } v;
    v.i = b;
    return v.f;
}
__device__ __forceinline__ unsigned short f2b(float f) {  // round-nearest-even
    union { float f; unsigned int i; } v;
    v.f = f;
    unsigned int r = v.i + 0x7FFFu + ((v.i >> 16) & 1u);
    return (unsigned short)(r >> 16);
}

// ---------------------------------------------------------------------------
// Unified prep + edge scatter. Scatter blocks FIRST so they start early.
// ---------------------------------------------------------------------------
__global__ __launch_bounds__(256) void prep_scatter(
    const float* __restrict__ x,
    const float* __restrict__ W11, const float* __restrict__ W12,
    const float* __restrict__ W21, const float* __restrict__ W22,
    const float* __restrict__ Wfc,
    const int* __restrict__ srcv, const int* __restrict__ dstv,
    unsigned short* __restrict__ xb,
    unsigned short* __restrict__ Wt11, unsigned short* __restrict__ Wt12,
    unsigned short* __restrict__ Wt21, unsigned short* __restrict__ Wt22,
    unsigned short* __restrict__ Wfct,
    int* __restrict__ cnt, int* __restrict__ tmp) {
    const int bid = blockIdx.x;
    const int tid = threadIdx.x;
    if (bid < NSB) {
        __shared__ int hist[NBUCK];
        const int k = bid;
        const int e0 = k * EPB;
        for (int i = tid; i < NBUCK; i += 256) hist[i] = 0;
        __syncthreads();
#pragma unroll
        for (int j = 0; j < EPB / 256; ++j) {
            int e = e0 + j * 256 + tid;
            if (e < N_EDGES) atomicAdd(&hist[dstv[e] >> 9], 1);
        }
        __syncthreads();
        for (int i = tid; i < NBUCK; i += 256) {
            cnt[i * NSB + k] = hist[i];
            hist[i] = 0;
        }
        __syncthreads();
#pragma unroll
        for (int j = 0; j < EPB / 256; ++j) {
            int e = e0 + j * 256 + tid;
            if (e < N_EDGES) {
                int d = dstv[e];
                int b = d >> 9;
                int r = atomicAdd(&hist[b], 1);
                if (r < BCAP)
                    tmp[((size_t)k * NBUCK + b) * BCAP + r] = srcv[e] | ((d & 511) << 16);
            }
        }
    } else if (bid < NSB + 512) {
        int wb = bid - NSB;
        int which = wb >> 7;
        int idx = (wb & 127) * 256 + tid;
        const float* W = (which == 0) ? W11 : (which == 1) ? W12 : (which == 2) ? W21 : W22;
        unsigned short* Wt = (which == 0) ? Wt11 : (which == 1) ? Wt12 : (which == 2) ? Wt21 : Wt22;
        int K = (which & 1) ? 256 : 128;
        int N = (which & 1) ? 128 : 256;
        int k = idx / N, n = idx - k * N;
        Wt[n * K + k] = f2b(W[idx]);
    } else if (bid < NSB + 536) {
        int idx = (bid - NSB - 512) * 256 + tid;     // 6144 = 48*128
        int n = idx >> 7, k = idx & 127;
        Wfct[idx] = (n < 40) ? f2b(Wfc[k * 40 + n]) : (unsigned short)0;
    } else {
        int i = (bid - NSB - 536) * 256 + tid;       // 800000 groups of 8
        const float4 a = *reinterpret_cast<const float4*>(x + (size_t)i * 8);
        const float4 b = *reinterpret_cast<const float4*>(x + (size_t)i * 8 + 4);
        ushort4 u0, u1;
        u0.x = f2b(a.x); u0.y = f2b(a.y); u0.z = f2b(a.z); u0.w = f2b(a.w);
        u1.x = f2b(b.x); u1.y = f2b(b.y); u1.z = f2b(b.z); u1.w = f2b(b.w);
        *reinterpret_cast<ushort4*>(xb + (size_t)i * 8) = u0;
        *reinterpret_cast<ushort4*>(xb + (size_t)i * 8 + 4) = u1;
    }
}

// ---------------------------------------------------------------------------
// per-bucket: stage 391 strips, derive row_ptr (513-strided, local scan),
// sort edges into CSR order, write bucket-strided e_src (base b*CAPB).
// ---------------------------------------------------------------------------
__global__ __launch_bounds__(256) void bucket_sort_ex(const int* __restrict__ cnt,
                                                      const int* __restrict__ tmp,
                                                      int* __restrict__ e_src,
                                                      int* __restrict__ row_ptr) {
    __shared__ int ps[256];
    __shared__ int sb[512];
    __shared__ int sc[512];
    __shared__ int nc[512];
    __shared__ int buf[CAPB];
    const int tid = threadIdx.x;
    const int b = blockIdx.x;

    sc[tid] = (tid < NSB) ? cnt[b * NSB + tid] : 0;
    sc[tid + 256] = (tid + 256 < NSB) ? cnt[b * NSB + tid + 256] : 0;
    __syncthreads();
    const int c0s = sc[2 * tid], c1s = sc[2 * tid + 1];
    ps[tid] = c0s + c1s;
    __syncthreads();
    for (int off = 1; off < 256; off <<= 1) {
        int u = (tid >= off) ? ps[tid - off] : 0;
        __syncthreads();
        ps[tid] += u;
        __syncthreads();
    }
    const int soff0 = ps[tid] - (c0s + c1s);
    sb[2 * tid] = soff0;
    sb[2 * tid + 1] = soff0 + c0s;
    __syncthreads();
    const int S = ps[255];

    const int lane = tid & 63, w = tid >> 6;
    const int hw = w * 2 + (lane >> 5), hl = lane & 31;
    for (int k = hw; k < NSB; k += 8) {
        const int base = sb[k], c = sc[k];
        const int* src = tmp + ((size_t)k * NBUCK + b) * BCAP;
        for (int i = hl; i < c; i += 32)
            if (base + i < CAPB) buf[base + i] = src[i];
    }
    for (int i = tid; i < 512; i += 256) nc[i] = 0;
    __syncthreads();
    for (int e = tid; e < S; e += 256)
        atomicAdd(&nc[(buf[e] >> 16) & 511], 1);
    __syncthreads();

    const int c0 = nc[2 * tid], c1 = nc[2 * tid + 1];
    ps[tid] = c0 + c1;
    __syncthreads();
    for (int off = 1; off < 256; off <<= 1) {
        int u = (tid >= off) ? ps[tid - off] : 0;
        __syncthreads();
        ps[tid] += u;
        __syncthreads();
    }
    const int off0 = ps[tid] - (c0 + c1);
    const int off1 = off0 + c0;
    nc[2 * tid] = off0;
    nc[2 * tid + 1] = off1;
    const int gbase = b * CAPB;
    row_ptr[b * 513 + 2 * tid] = gbase + off0;
    row_ptr[b * 513 + 2 * tid + 1] = gbase + off1;
    if (tid == 0) row_ptr[b * 513 + 512] = gbase + S;
    __syncthreads();

    for (int e = tid; e < S; e += 256) {
        int p = buf[e];
        int dl = (p >> 16) & 511;
        int pos = atomicAdd(&nc[dl], 1);
        e_src[gbase + pos] = p & 0xFFFF;
    }
}

// ---------------------------------------------------------------------------
// aggregate (round-11 winner): one wave/node, quarter-wave split, 4 streams,
// unroll x4 -> 16 row-loads in flight. row_ptr is 513-strided per bucket.
// ---------------------------------------------------------------------------
__global__ __launch_bounds__(256) void agg_bf16q(const unsigned short* __restrict__ X,
                                                 const int* __restrict__ row_ptr,
                                                 const int* __restrict__ e_src,
                                                 unsigned short* __restrict__ agg) {
    const int node = (blockIdx.x * 256 + threadIdx.x) >> 6;
    const int lane = threadIdx.x & 63;
    const int qw = lane >> 4, ql = lane & 15;
    const size_t off = (size_t)ql * 8;

    const int rp = node + (node >> 9);
    const int beg = row_ptr[rp], end = row_ptr[rp + 1];
    float acc[8];
#pragma unroll
    for (int k = 0; k < 8; ++k) acc[k] = 0.f;

    if (qw == 0) {
        uint4 u = *reinterpret_cast<const uint4*>(X + (size_t)node * 128 + off);
        const unsigned int* up = (const unsigned int*)&u;
#pragma unroll
        for (int k = 0; k < 4; ++k) {
            acc[2 * k]     += ubits(up[k] << 16);
            acc[2 * k + 1] += ubits(up[k] & 0xFFFF0000u);
        }
    }

    int e = beg + qw;
    for (; e + 12 < end; e += 16) {
        const int s0 = e_src[e], s1 = e_src[e + 4], s2 = e_src[e + 8], s3 = e_src[e + 12];
        uint4 u0 = *reinterpret_cast<const uint4*>(X + (size_t)s0 * 128 + off);
        uint4 u1 = *reinterpret_cast<const uint4*>(X + (size_t)s1 * 128 + off);
        uint4 u2 = *reinterpret_cast<const uint4*>(X + (size_t)s2 * 128 + off);
        uint4 u3 = *reinterpret_cast<const uint4*>(X + (size_t)s3 * 128 + off);
        const unsigned int* p0 = (const unsigned int*)&u0;
        const unsigned int* p1 = (const unsigned int*)&u1;
        const unsigned int* p2 = (const unsigned int*)&u2;
        const unsigned int* p3 = (const unsigned int*)&u3;
#pragma unroll
        for (int k = 0; k < 4; ++k) {
            acc[2 * k]     += ubits(p0[k] << 16) + ubits(p1[k] << 16)
                            + ubits(p2[k] << 16) + ubits(p3[k] << 16);
            acc[2 * k + 1] += ubits(p0[k] & 0xFFFF0000u) + ubits(p1[k] & 0xFFFF0000u)
                            + ubits(p2[k] & 0xFFFF0000u) + ubits(p3[k] & 0xFFFF0000u);
        }
    }
    for (; e + 4 < end; e += 8) {
        const int s0 = e_src[e], s1 = e_src[e + 4];
        uint4 u0 = *reinterpret_cast<const uint4*>(X + (size_t)s0 * 128 + off);
        uint4 u1 = *reinterpret_cast<const uint4*>(X + (size_t)s1 * 128 + off);
        const unsigned int* p0 = (const unsigned int*)&u0;
        const unsigned int* p1 = (const unsigned int*)&u1;
#pragma unroll
        for (int k = 0; k < 4; ++k) {
            acc[2 * k]     += ubits(p0[k] << 16) + ubits(p1[k] << 16);
            acc[2 * k + 1] += ubits(p0[k] & 0xFFFF0000u) + ubits(p1[k] & 0xFFFF0000u);
        }
    }
    if (e < end) {
        const int s = e_src[e];
        uint4 u = *reinterpret_cast<const uint4*>(X + (size_t)s * 128 + off);
        const unsigned int* p = (const unsigned int*)&u;
#pragma unroll
        for (int k = 0; k < 4; ++k) {
            acc[2 * k]     += ubits(p[k] << 16);
            acc[2 * k + 1] += ubits(p[k] & 0xFFFF0000u);
        }
    }

#pragma unroll
    for (int k = 0; k < 8; ++k) acc[k] += __shfl_xor(acc[k], 32);
#pragma unroll
    for (int k = 0; k < 8; ++k) acc[k] += __shfl_xor(acc[k], 16);

    if (qw == 0) {
        ushort4 o0, o1;
        o0.x = f2b(acc[0]); o0.y = f2b(acc[1]); o0.z = f2b(acc[2]); o0.w = f2b(acc[3]);
        o1.x = f2b(acc[4]); o1.y = f2b(acc[5]); o1.z = f2b(acc[6]); o1.w = f2b(acc[7]);
        unsigned short* p = agg + (size_t)node * 128 + off;
        *reinterpret_cast<ushort4*>(p) = o0;
        *reinterpret_cast<ushort4*>(p + 4) = o1;
    }
}

// ---------------------------------------------------------------------------
// Fused MLP with software-pipelined weight staging: next W chunk is
// prefetched into registers during the current chunk's MFMAs, stored to LDS
// at the existing barriers. Same barrier count; loads overlap compute.
// LDS layout (bytes):
//   [0,     17408): A[64][136]      | stage2: B2q[32][264] (16896)
//   [17408, 52224): B1h[128][136]   | stage2: T[64][264]   (33792)
//   [52224, 57344): Hc[64][40]      (FUSE only)
// ---------------------------------------------------------------------------
template <bool FUSE>
__global__ __launch_bounds__(256, FUSE ? 2 : 3) void mlp_fused(
    const unsigned short* __restrict__ X, const unsigned short* __restrict__ Wt1,
    const float* __restrict__ b1, const unsigned short* __restrict__ Wt2,
    const float* __restrict__ b2, unsigned short* __restrict__ Y,
    const unsigned short* __restrict__ Wfct, const float* __restrict__ bfc,
    float* __restrict__ out, int M) {
    __shared__ __align__(16) char smem[FUSE ? 57344 : 52224];
    unsigned short* A   = (unsigned short*)smem;             // [64][136]
    unsigned short* B2q = (unsigned short*)smem;             // [32][264]
    unsigned short* B1h = (unsigned short*)(smem + 17408);   // [128][136]
    unsigned short* T   = (unsigned short*)(smem + 17408);   // [64][264]
    unsigned short* Hc  = (unsigned short*)(smem + 52224);   // [64][40]

    const int tid = threadIdx.x;
    const int m0 = blockIdx.x * 64;
    const int lane = tid & 63, w = tid >> 6;
    const int qm = lane & 15, quad = lane >> 4;

    // ---- load A (64 x 128 bf16) ----
#pragma unroll
    for (int j = 0; j < 4; ++j) {
        int i = j * 256 + tid;
        int r = i >> 4, c8 = (i & 15) << 3;
        uint4 v = {0, 0, 0, 0};
        if (m0 + r < M) v = *reinterpret_cast<const uint4*>(X + (size_t)(m0 + r) * 128 + c8);
        *reinterpret_cast<uint4*>(&A[r * 136 + c8]) = v;
    }

    // ---- stage 1: W1 chunk 0 -> LDS, chunk 1 -> regs (overlaps MFMAs) ----
    floatx4 acc1[2][4][2];
#pragma unroll
    for (int c = 0; c < 2; ++c)
#pragma unroll
        for (int mt = 0; mt < 4; ++mt)
#pragma unroll
            for (int nt = 0; nt < 2; ++nt) acc1[c][mt][nt] = {0.f, 0.f, 0.f, 0.f};

#pragma unroll
    for (int j = 0; j < 8; ++j) {
        int i = j * 256 + tid;
        int r = i >> 4, c8 = (i & 15) << 3;
        *reinterpret_cast<uint4*>(&B1h[r * 136 + c8]) =
            *reinterpret_cast<const uint4*>(Wt1 + (size_t)r * 128 + c8);
    }
    uint4 wpre[8];
#pragma unroll
    for (int j = 0; j < 8; ++j) {
        int i = j * 256 + tid;
        int r = i >> 4, c8 = (i & 15) << 3;
        wpre[j] = *reinterpret_cast<const uint4*>(Wt1 + (size_t)(128 + r) * 128 + c8);
    }
    __syncthreads();
#pragma unroll
    for (int ks = 0; ks < 4; ++ks) {
        const int kb = ks * 32 + quad * 8;
        short8 a[4], b[2];
#pragma unroll
        for (int mt = 0; mt < 4; ++mt)
            a[mt] = *reinterpret_cast<const short8*>(&A[(mt * 16 + qm) * 136 + kb]);
#pragma unroll
        for (int nt = 0; nt < 2; ++nt)
            b[nt] = *reinterpret_cast<const short8*>(&B1h[(w * 32 + nt * 16 + qm) * 136 + kb]);
#pragma unroll
        for (int mt = 0; mt < 4; ++mt)
#pragma unroll
            for (int nt = 0; nt < 2; ++nt)
                acc1[0][mt][nt] = __builtin_amdgcn_mfma_f32_16x16x32_bf16(
                    a[mt], b[nt], acc1[0][mt][nt], 0, 0, 0);
    }
    __syncthreads();
#pragma unroll
    for (int j = 0; j < 8; ++j) {
        int i = j * 256 + tid;
        int r = i >> 4, c8 = (i & 15) << 3;
        *reinterpret_cast<uint4*>(&B1h[r * 136 + c8]) = wpre[j];
    }
    // prefetch W2 chunk 0 (overlaps stage-1 chunk-1 MFMAs)
    uint4 bpre[4];
#pragma unroll
    for (int j = 0; j < 4; ++j) {
        int i = j * 256 + tid;
        int r = i >> 5, c8 = (i & 31) << 3;
        bpre[j] = *reinterpret_cast<const uint4*>(Wt2 + (size_t)r * 256 + c8);
    }
    __syncthreads();
#pragma unroll
    for (int ks = 0; ks < 4; ++ks) {
        const int kb = ks * 32 + quad * 8;
        short8 a[4], b[2];
#pragma unroll
        for (int mt = 0; mt < 4; ++mt)
            a[mt] = *reinterpret_cast<const short8*>(&A[(mt * 16 + qm) * 136 + kb]);
#pragma unroll
        for (int nt = 0; nt < 2; ++nt)
            b[nt] = *reinterpret_cast<const short8*>(&B1h[(w * 32 + nt * 16 + qm) * 136 + kb]);
#pragma unroll
        for (int mt = 0; mt < 4; ++mt)
#pragma unroll
            for (int nt = 0; nt < 2; ++nt)
                acc1[1][mt][nt] = __builtin_amdgcn_mfma_f32_16x16x32_bf16(
                    a[mt], b[nt], acc1[1][mt][nt], 0, 0, 0);
    }
    __syncthreads();   // all A / B1h reads done; safe to overwrite with T / B2q

    // ---- epilogue 1: T (bf16, LDS) = relu(acc1 + b1); B2q <- W2 chunk 0 ----
#pragma unroll
    for (int c = 0; c < 2; ++c) {
#pragma unroll
        for (int nt = 0; nt < 2; ++nt) {
            const int jcol = c * 128 + w * 32 + nt * 16 + qm;
            const float bj = b1[jcol];
#pragma unroll
            for (int mt = 0; mt < 4; ++mt)
#pragma unroll
                for (int r = 0; r < 4; ++r)
                    T[(mt * 16 + quad * 4 + r) * 264 + jcol] =
                        f2b(fmaxf(acc1[c][mt][nt][r] + bj, 0.f));
        }
    }
#pragma unroll
    for (int j = 0; j < 4; ++j) {
        int i = j * 256 + tid;
        int r = i >> 5, c8 = (i & 31) << 3;
        *reinterpret_cast<uint4*>(&B2q[r * 264 + c8]) = bpre[j];
    }
    __syncthreads();

    // ---- stage 2: h = relu(T @ W2 + b2); W2 chunks software-pipelined ----
    floatx4 cacc[3];
#pragma unroll
    for (int nt = 0; nt < 3; ++nt) cacc[nt] = {0.f, 0.f, 0.f, 0.f};

#pragma unroll
    for (int c2 = 0; c2 < 4; ++c2) {
        if (c2 < 3) {
#pragma unroll
            for (int j = 0; j < 4; ++j) {
                int i = j * 256 + tid;
                int r = i >> 5, c8 = (i & 31) << 3;
                bpre[j] = *reinterpret_cast<const uint4*>(
                    Wt2 + (size_t)((c2 + 1) * 32 + r) * 256 + c8);
            }
        }

        floatx4 acc2[2];
        acc2[0] = {0.f, 0.f, 0.f, 0.f};
        acc2[1] = {0.f, 0.f, 0.f, 0.f};
#pragma unroll
        for (int ks = 0; ks < 8; ++ks) {
            const int kb = ks * 32 + quad * 8;
            short8 t0 = *reinterpret_cast<const short8*>(&T[((w & 1) * 32 + qm) * 264 + kb]);
            short8 t1 = *reinterpret_cast<const short8*>(&T[((w & 1) * 32 + 16 + qm) * 264 + kb]);
            short8 bb = *reinterpret_cast<const short8*>(&B2q[((w >> 1) * 16 + qm) * 264 + kb]);
            acc2[0] = __builtin_amdgcn_mfma_f32_16x16x32_bf16(t0, bb, acc2[0], 0, 0, 0);
            acc2[1] = __builtin_amdgcn_mfma_f32_16x16x32_bf16(t1, bb, acc2[1], 0, 0, 0);
        }

        const int ncol = c2 * 32 + (w >> 1) * 16 + qm;   // global h col
        const float bj = b2[ncol];
        if (!FUSE) {
#pragma unroll
            for (int mt2 = 0; mt2 < 2; ++mt2)
#pragma unroll
                for (int r = 0; r < 4; ++r) {
                    int row = m0 + (w & 1) * 32 + mt2 * 16 + quad * 4 + r;
                    if (row < M)
                        Y[(size_t)row * 128 + ncol] = f2b(fmaxf(acc2[mt2][r] + bj, 0.f));
                }
            if (c2 < 3) {
                __syncthreads();            // B2q readers done
#pragma unroll
                for (int j = 0; j < 4; ++j) {
                    int i = j * 256 + tid;
                    int r = i >> 5, c8 = (i & 31) << 3;
                    *reinterpret_cast<uint4*>(&B2q[r * 264 + c8]) = bpre[j];
                }
                __syncthreads();
            }
        } else {
            const int lcol = (w >> 1) * 16 + qm;
#pragma unroll
            for (int mt2 = 0; mt2 < 2; ++mt2)
#pragma unroll
                for (int r = 0; r < 4; ++r)
                    Hc[((w & 1) * 32 + mt2 * 16 + quad * 4 + r) * 40 + lcol] =
                        f2b(fmaxf(acc2[mt2][r] + bj, 0.f));
            __syncthreads();                // Hc ready; B2q readers done
            short8 hf = *reinterpret_cast<const short8*>(&Hc[(w * 16 + qm) * 40 + quad * 8]);
#pragma unroll
            for (int nt = 0; nt < 3; ++nt) {
                short8 bf = *reinterpret_cast<const short8*>(
                    Wfct + (nt * 16 + qm) * 128 + c2 * 32 + quad * 8);
                cacc[nt] = __builtin_amdgcn_mfma_f32_16x16x32_bf16(hf, bf, cacc[nt], 0, 0, 0);
            }
            if (c2 < 3) {
#pragma unroll
                for (int j = 0; j < 4; ++j) {
                    int i = j * 256 + tid;
                    int r = i >> 5, c8 = (i & 31) << 3;
                    *reinterpret_cast<uint4*>(&B2q[r * 264 + c8]) = bpre[j];
                }
            }
            __syncthreads();                // B2q ready; Hc free for next c2
        }
    }

    if (FUSE) {
#pragma unroll
        for (int nt = 0; nt < 3; ++nt) {
            int col = nt * 16 + qm;
            if (col < 40) {
                const float bj = bfc[col];
#pragma unroll
                for (int r = 0; r < 4; ++r) {
                    int row = m0 + w * 16 + quad * 4 + r;
                    if (row < M) out[(size_t)row * 40 + col] = cacc[nt][r] + bj;
                }
            }
        }
    }
}

// ---------------------------------------------------------------------------
extern "C" void kernel_launch(void* const* d_in, const int* in_sizes, int n_in,
                              void* d_out, int out_size, void* d_ws, size_t ws_size,
                              hipStream_t stream) {
    const float* x   = (const float*)d_in[0];
    const int*   ei  = (const int*)d_in[1];
    const float* W11 = (const float*)d_in[2];
    const float* b11 = (const float*)d_in[3];
    const float* W12 = (const float*)d_in[4];
    const float* b12 = (const float*)d_in[5];
    const float* W21 = (const float*)d_in[6];
    const float* b21 = (const float*)d_in[7];
    const float* W22 = (const float*)d_in[8];
    const float* b22 = (const float*)d_in[9];
    const float* Wfc = (const float*)d_in[10];
    const float* bfc = (const float*)d_in[11];
    float* out = (float*)d_out;

    const int* srcv = ei;
    const int* dstv = ei + N_EDGES;

    unsigned short* agg  = (unsigned short*)d_ws;               // 50000*128 bf16
    unsigned short* h    = agg + (size_t)N_NODES * 128;         // 50000*128 bf16
    unsigned short* xb   = h   + (size_t)N_NODES * 128;         // 50000*128 bf16
    unsigned short* Wt11 = xb  + (size_t)N_NODES * 128;
    unsigned short* Wt12 = Wt11 + 256 * 128;
    unsigned short* Wt21 = Wt12 + 256 * 128;
    unsigned short* Wt22 = Wt21 + 256 * 128;
    unsigned short* Wfct = Wt22 + 256 * 128;                    // 48*128
    int* cnt     = (int*)(Wfct + 48 * 128);                     // 98*391 (pad 38400)
    int* row_ptr = cnt + 38400;                                 // 98*513 (pad 50304)
    int* e_src   = row_ptr + 50304;                             // 98*12288
    int* tmp     = e_src + (size_t)NBUCK * CAPB;                // 391*98*64 = 2.45M

    // ---- prep (weights + Wfc + x->bf16) + edge scatter, one kernel ----
    prep_scatter<<<NSB + 3661, 256, 0, stream>>>(
        x, W11, W12, W21, W22, Wfc, srcv, dstv,
        xb, Wt11, Wt12, Wt21, Wt22, Wfct, cnt, tmp);

    // ---- per-bucket CSR sort (independent buckets, no global scan) ----
    bucket_sort_ex<<<NBUCK, 256, 0, stream>>>(cnt, tmp, e_src, row_ptr);

    const int agg_blocks = N_NODES * 64 / 256;        // 12500, one wave per node
    const int mlp_blocks = (N_NODES + 63) / 64;       // 782

    // ---- layer 1 ----
    agg_bf16q<<<agg_blocks, 256, 0, stream>>>(xb, row_ptr, e_src, agg);
    mlp_fused<false><<<mlp_blocks, 256, 0, stream>>>(
        agg, Wt11, b11, Wt12, b12, h, nullptr, nullptr, nullptr, N_NODES);
    // ---- layer 2 + classifier ----
    agg_bf16q<<<agg_blocks, 256, 0, stream>>>(h, row_ptr, e_src, agg);
    mlp_fused<true><<<mlp_blocks, 256, 0, stream>>>(
        agg, Wt21, b21, Wt22, b22, nullptr, Wfct, bfc, out, N_NODES);
}

// Round 14
// 244.972 us; speedup vs baseline: 1.1466x; 1.1466x over previous
//
#include <hip/hip_runtime.h>

#define N_NODES 50000
#define N_EDGES 800000
#define NBUCK   98            // buckets of 512 nodes (dst >> 9)
#define EPB     2048          // edges per scatter block
#define NSB     391           // scatter blocks = ceil(800000/2048)
#define BCAP    64            // per-(block,bucket) strip capacity (mean ~21)
#define CAPB    12288         // per-bucket e_src capacity (~8163 mean)

typedef __attribute__((ext_vector_type(8))) short short8;
typedef __attribute__((ext_vector_type(4))) float floatx4;

__device__ __forceinline__ float b2f(unsigned short u) {
    union { unsigned int i; float f; } v;
    v.i = ((unsigned int)u) << 16;
    return v.f;
}
__device__ __forceinline__ float ubits(unsigned int b) {
    union { unsigned int i; float f; } v;
    v.i = b;
    return v.f;
}
__device__ __forceinline__ unsigned short f2b(float f) {  // round-nearest-even
    union { float f; unsigned int i; } v;
    v.f = f;
    unsigned int r = v.i + 0x7FFFu + ((v.i >> 16) & 1u);
    return (unsigned short)(r >> 16);
}

// ---------------------------------------------------------------------------
// Unified prep + edge scatter. Scatter blocks FIRST so they start early:
// [0,391): scatter block k -> strips tmp[(k*98+b)*BCAP+r], counts cnt[b*391+k]
// [391,903): weights -> Wt bf16.  [903,927): Wfc -> Wfct[48][128].
// [927,4052): x -> bf16.
// ---------------------------------------------------------------------------
__global__ __launch_bounds__(256) void prep_scatter(
    const float* __restrict__ x,
    const float* __restrict__ W11, const float* __restrict__ W12,
    const float* __restrict__ W21, const float* __restrict__ W22,
    const float* __restrict__ Wfc,
    const int* __restrict__ srcv, const int* __restrict__ dstv,
    unsigned short* __restrict__ xb,
    unsigned short* __restrict__ Wt11, unsigned short* __restrict__ Wt12,
    unsigned short* __restrict__ Wt21, unsigned short* __restrict__ Wt22,
    unsigned short* __restrict__ Wfct,
    int* __restrict__ cnt, int* __restrict__ tmp) {
    const int bid = blockIdx.x;
    const int tid = threadIdx.x;
    if (bid < NSB) {
        // ---- scatter block ----
        __shared__ int hist[NBUCK];
        const int k = bid;
        const int e0 = k * EPB;
        for (int i = tid; i < NBUCK; i += 256) hist[i] = 0;
        __syncthreads();
#pragma unroll
        for (int j = 0; j < EPB / 256; ++j) {
            int e = e0 + j * 256 + tid;
            if (e < N_EDGES) atomicAdd(&hist[dstv[e] >> 9], 1);
        }
        __syncthreads();
        for (int i = tid; i < NBUCK; i += 256) {
            cnt[i * NSB + k] = hist[i];
            hist[i] = 0;
        }
        __syncthreads();
#pragma unroll
        for (int j = 0; j < EPB / 256; ++j) {
            int e = e0 + j * 256 + tid;
            if (e < N_EDGES) {
                int d = dstv[e];
                int b = d >> 9;
                int r = atomicAdd(&hist[b], 1);
                if (r < BCAP)
                    tmp[((size_t)k * NBUCK + b) * BCAP + r] = srcv[e] | ((d & 511) << 16);
            }
        }
    } else if (bid < NSB + 512) {
        int wb = bid - NSB;
        int which = wb >> 7;
        int idx = (wb & 127) * 256 + tid;
        const float* W = (which == 0) ? W11 : (which == 1) ? W12 : (which == 2) ? W21 : W22;
        unsigned short* Wt = (which == 0) ? Wt11 : (which == 1) ? Wt12 : (which == 2) ? Wt21 : Wt22;
        int K = (which & 1) ? 256 : 128;
        int N = (which & 1) ? 128 : 256;
        int k = idx / N, n = idx - k * N;
        Wt[n * K + k] = f2b(W[idx]);
    } else if (bid < NSB + 536) {
        int idx = (bid - NSB - 512) * 256 + tid;     // 6144 = 48*128
        int n = idx >> 7, k = idx & 127;
        Wfct[idx] = (n < 40) ? f2b(Wfc[k * 40 + n]) : (unsigned short)0;
    } else {
        int i = (bid - NSB - 536) * 256 + tid;       // 800000 groups of 8
        const float4 a = *reinterpret_cast<const float4*>(x + (size_t)i * 8);
        const float4 b = *reinterpret_cast<const float4*>(x + (size_t)i * 8 + 4);
        ushort4 u0, u1;
        u0.x = f2b(a.x); u0.y = f2b(a.y); u0.z = f2b(a.z); u0.w = f2b(a.w);
        u1.x = f2b(b.x); u1.y = f2b(b.y); u1.z = f2b(b.z); u1.w = f2b(b.w);
        *reinterpret_cast<ushort4*>(xb + (size_t)i * 8) = u0;
        *reinterpret_cast<ushort4*>(xb + (size_t)i * 8 + 4) = u1;
    }
}

// ---------------------------------------------------------------------------
// per-bucket: stage 391 strips, derive row_ptr (513-strided, local scan),
// sort edges into CSR order, write bucket-strided e_src (base b*CAPB).
// ---------------------------------------------------------------------------
__global__ __launch_bounds__(256) void bucket_sort_ex(const int* __restrict__ cnt,
                                                      const int* __restrict__ tmp,
                                                      int* __restrict__ e_src,
                                                      int* __restrict__ row_ptr) {
    __shared__ int ps[256];
    __shared__ int sb[512];      // strip bases (padded)
    __shared__ int sc[512];      // strip counts (padded)
    __shared__ int nc[512];      // node counts -> cursors
    __shared__ int buf[CAPB];
    const int tid = threadIdx.x;
    const int b = blockIdx.x;

    // load strip counts (padded to 512) and pair-sum exclusive scan
    sc[tid] = (tid < NSB) ? cnt[b * NSB + tid] : 0;
    sc[tid + 256] = (tid + 256 < NSB) ? cnt[b * NSB + tid + 256] : 0;
    __syncthreads();
    const int c0s = sc[2 * tid], c1s = sc[2 * tid + 1];
    ps[tid] = c0s + c1s;
    __syncthreads();
    for (int off = 1; off < 256; off <<= 1) {
        int u = (tid >= off) ? ps[tid - off] : 0;
        __syncthreads();
        ps[tid] += u;
        __syncthreads();
    }
    const int soff0 = ps[tid] - (c0s + c1s);
    sb[2 * tid] = soff0;
    sb[2 * tid + 1] = soff0 + c0s;
    __syncthreads();
    const int S = ps[255];

    // stage strips into buf: half-wave (32 lanes) per strip
    const int lane = tid & 63, w = tid >> 6;
    const int hw = w * 2 + (lane >> 5), hl = lane & 31;
    for (int k = hw; k < NSB; k += 8) {
        const int base = sb[k], c = sc[k];
        const int* src = tmp + ((size_t)k * NBUCK + b) * BCAP;
        for (int i = hl; i < c; i += 32)
            if (base + i < CAPB) buf[base + i] = src[i];
    }
    // node histogram
    for (int i = tid; i < 512; i += 256) nc[i] = 0;
    __syncthreads();
    for (int e = tid; e < S; e += 256)
        atomicAdd(&nc[(buf[e] >> 16) & 511], 1);
    __syncthreads();

    // exclusive scan of nc[512] via pair-sums
    const int c0 = nc[2 * tid], c1 = nc[2 * tid + 1];
    ps[tid] = c0 + c1;
    __syncthreads();
    for (int off = 1; off < 256; off <<= 1) {
        int u = (tid >= off) ? ps[tid - off] : 0;
        __syncthreads();
        ps[tid] += u;
        __syncthreads();
    }
    const int off0 = ps[tid] - (c0 + c1);
    const int off1 = off0 + c0;
    nc[2 * tid] = off0;
    nc[2 * tid + 1] = off1;
    const int gbase = b * CAPB;
    row_ptr[b * 513 + 2 * tid] = gbase + off0;
    row_ptr[b * 513 + 2 * tid + 1] = gbase + off1;
    if (tid == 0) row_ptr[b * 513 + 512] = gbase + S;
    __syncthreads();

    // place
    for (int e = tid; e < S; e += 256) {
        int p = buf[e];
        int dl = (p >> 16) & 511;
        int pos = atomicAdd(&nc[dl], 1);
        e_src[gbase + pos] = p & 0xFFFF;
    }
}

// ---------------------------------------------------------------------------
// aggregate: agg[i] = x[i] + sum_{e in row i} x[e_src[e]]  — one wave/node.
// Quarter-wave split (16 lanes x ushort8 = 256B row), 4 edge streams/wave,
// unroll x4 -> 16 row-loads in flight. row_ptr is 513-strided per bucket.
// ---------------------------------------------------------------------------
__global__ __launch_bounds__(256) void agg_bf16q(const unsigned short* __restrict__ X,
                                                 const int* __restrict__ row_ptr,
                                                 const int* __restrict__ e_src,
                                                 unsigned short* __restrict__ agg) {
    const int node = (blockIdx.x * 256 + threadIdx.x) >> 6;
    const int lane = threadIdx.x & 63;
    const int qw = lane >> 4, ql = lane & 15;
    const size_t off = (size_t)ql * 8;

    const int rp = node + (node >> 9);
    const int beg = row_ptr[rp], end = row_ptr[rp + 1];
    float acc[8];
#pragma unroll
    for (int k = 0; k < 8; ++k) acc[k] = 0.f;

    if (qw == 0) {
        uint4 u = *reinterpret_cast<const uint4*>(X + (size_t)node * 128 + off);
        const unsigned int* up = (const unsigned int*)&u;
#pragma unroll
        for (int k = 0; k < 4; ++k) {
            acc[2 * k]     += ubits(up[k] << 16);
            acc[2 * k + 1] += ubits(up[k] & 0xFFFF0000u);
        }
    }

    int e = beg + qw;
    for (; e + 12 < end; e += 16) {
        const int s0 = e_src[e], s1 = e_src[e + 4], s2 = e_src[e + 8], s3 = e_src[e + 12];
        uint4 u0 = *reinterpret_cast<const uint4*>(X + (size_t)s0 * 128 + off);
        uint4 u1 = *reinterpret_cast<const uint4*>(X + (size_t)s1 * 128 + off);
        uint4 u2 = *reinterpret_cast<const uint4*>(X + (size_t)s2 * 128 + off);
        uint4 u3 = *reinterpret_cast<const uint4*>(X + (size_t)s3 * 128 + off);
        const unsigned int* p0 = (const unsigned int*)&u0;
        const unsigned int* p1 = (const unsigned int*)&u1;
        const unsigned int* p2 = (const unsigned int*)&u2;
        const unsigned int* p3 = (const unsigned int*)&u3;
#pragma unroll
        for (int k = 0; k < 4; ++k) {
            acc[2 * k]     += ubits(p0[k] << 16) + ubits(p1[k] << 16)
                            + ubits(p2[k] << 16) + ubits(p3[k] << 16);
            acc[2 * k + 1] += ubits(p0[k] & 0xFFFF0000u) + ubits(p1[k] & 0xFFFF0000u)
                            + ubits(p2[k] & 0xFFFF0000u) + ubits(p3[k] & 0xFFFF0000u);
        }
    }
    for (; e + 4 < end; e += 8) {
        const int s0 = e_src[e], s1 = e_src[e + 4];
        uint4 u0 = *reinterpret_cast<const uint4*>(X + (size_t)s0 * 128 + off);
        uint4 u1 = *reinterpret_cast<const uint4*>(X + (size_t)s1 * 128 + off);
        const unsigned int* p0 = (const unsigned int*)&u0;
        const unsigned int* p1 = (const unsigned int*)&u1;
#pragma unroll
        for (int k = 0; k < 4; ++k) {
            acc[2 * k]     += ubits(p0[k] << 16) + ubits(p1[k] << 16);
            acc[2 * k + 1] += ubits(p0[k] & 0xFFFF0000u) + ubits(p1[k] & 0xFFFF0000u);
        }
    }
    if (e < end) {
        const int s = e_src[e];
        uint4 u = *reinterpret_cast<const uint4*>(X + (size_t)s * 128 + off);
        const unsigned int* p = (const unsigned int*)&u;
#pragma unroll
        for (int k = 0; k < 4; ++k) {
            acc[2 * k]     += ubits(p[k] << 16);
            acc[2 * k + 1] += ubits(p[k] & 0xFFFF0000u);
        }
    }

#pragma unroll
    for (int k = 0; k < 8; ++k) acc[k] += __shfl_xor(acc[k], 32);
#pragma unroll
    for (int k = 0; k < 8; ++k) acc[k] += __shfl_xor(acc[k], 16);

    if (qw == 0) {
        ushort4 o0, o1;
        o0.x = f2b(acc[0]); o0.y = f2b(acc[1]); o0.z = f2b(acc[2]); o0.w = f2b(acc[3]);
        o1.x = f2b(acc[4]); o1.y = f2b(acc[5]); o1.z = f2b(acc[6]); o1.w = f2b(acc[7]);
        unsigned short* p = agg + (size_t)node * 128 + off;
        *reinterpret_cast<ushort4*>(p) = o0;
        *reinterpret_cast<ushort4*>(p + 4) = o1;
    }
}

// ---------------------------------------------------------------------------
// Fused MLP: Y = relu(relu(X@W1+b1)@W2+b2) for a 64-row strip, t kept in LDS.
// FUSE variant additionally computes out = h @ Wfct^T + bfc (classifier).
// LDS layout (bytes):
//   [0,     17408): A[64][136]      | stage2: B2q[32][264] (16896)
//   [17408, 52224): B1h[128][136]   | stage2: T[64][264]   (33792)
//   [52224, 57344): Hc[64][40]      (FUSE only)
// ---------------------------------------------------------------------------
template <bool FUSE>
__global__ __launch_bounds__(256, FUSE ? 2 : 3) void mlp_fused(
    const unsigned short* __restrict__ X, const unsigned short* __restrict__ Wt1,
    const float* __restrict__ b1, const unsigned short* __restrict__ Wt2,
    const float* __restrict__ b2, unsigned short* __restrict__ Y,
    const unsigned short* __restrict__ Wfct, const float* __restrict__ bfc,
    float* __restrict__ out, int M) {
    __shared__ __align__(16) char smem[FUSE ? 57344 : 52224];
    unsigned short* A   = (unsigned short*)smem;             // [64][136]
    unsigned short* B2q = (unsigned short*)smem;             // [32][264]
    unsigned short* B1h = (unsigned short*)(smem + 17408);   // [128][136]
    unsigned short* T   = (unsigned short*)(smem + 17408);   // [64][264]
    unsigned short* Hc  = (unsigned short*)(smem + 52224);   // [64][40]

    const int tid = threadIdx.x;
    const int m0 = blockIdx.x * 64;
    const int lane = tid & 63, w = tid >> 6;
    const int qm = lane & 15, quad = lane >> 4;

    // ---- load A (64 x 128 bf16) ----
#pragma unroll
    for (int j = 0; j < 4; ++j) {
        int i = j * 256 + tid;
        int r = i >> 4, c8 = (i & 15) << 3;
        uint4 v = {0, 0, 0, 0};
        if (m0 + r < M) v = *reinterpret_cast<const uint4*>(X + (size_t)(m0 + r) * 128 + c8);
        *reinterpret_cast<uint4*>(&A[r * 136 + c8]) = v;
    }

    // ---- stage 1: t[64][256] = relu(A @ W1 + b1), acc in VGPRs ----
    floatx4 acc1[2][4][2];
#pragma unroll
    for (int c = 0; c < 2; ++c)
#pragma unroll
        for (int mt = 0; mt < 4; ++mt)
#pragma unroll
            for (int nt = 0; nt < 2; ++nt) acc1[c][mt][nt] = {0.f, 0.f, 0.f, 0.f};

    for (int c = 0; c < 2; ++c) {
#pragma unroll
        for (int j = 0; j < 8; ++j) {
            int i = j * 256 + tid;
            int r = i >> 4, c8 = (i & 15) << 3;
            *reinterpret_cast<uint4*>(&B1h[r * 136 + c8]) =
                *reinterpret_cast<const uint4*>(Wt1 + (size_t)(c * 128 + r) * 128 + c8);
        }
        __syncthreads();
#pragma unroll
        for (int ks = 0; ks < 4; ++ks) {
            const int kb = ks * 32 + quad * 8;
            short8 a[4], b[2];
#pragma unroll
            for (int mt = 0; mt < 4; ++mt)
                a[mt] = *reinterpret_cast<const short8*>(&A[(mt * 16 + qm) * 136 + kb]);
#pragma unroll
            for (int nt = 0; nt < 2; ++nt)
                b[nt] = *reinterpret_cast<const short8*>(&B1h[(w * 32 + nt * 16 + qm) * 136 + kb]);
#pragma unroll
            for (int mt = 0; mt < 4; ++mt)
#pragma unroll
                for (int nt = 0; nt < 2; ++nt)
                    acc1[c][mt][nt] = __builtin_amdgcn_mfma_f32_16x16x32_bf16(
                        a[mt], b[nt], acc1[c][mt][nt], 0, 0, 0);
        }
        __syncthreads();
    }

    // ---- epilogue 1: T (bf16, LDS) = relu(acc1 + b1) ----
#pragma unroll
    for (int c = 0; c < 2; ++c) {
#pragma unroll
        for (int nt = 0; nt < 2; ++nt) {
            const int jcol = c * 128 + w * 32 + nt * 16 + qm;
            const float bj = b1[jcol];
#pragma unroll
            for (int mt = 0; mt < 4; ++mt)
#pragma unroll
                for (int r = 0; r < 4; ++r)
                    T[(mt * 16 + quad * 4 + r) * 264 + jcol] =
                        f2b(fmaxf(acc1[c][mt][nt][r] + bj, 0.f));
        }
    }

    // ---- stage 2: h = relu(T @ W2 + b2), W2 streamed in 4x32-row chunks ----
    floatx4 cacc[3];
#pragma unroll
    for (int nt = 0; nt < 3; ++nt) cacc[nt] = {0.f, 0.f, 0.f, 0.f};

    for (int c2 = 0; c2 < 4; ++c2) {
#pragma unroll
        for (int j = 0; j < 4; ++j) {
            int i = j * 256 + tid;
            int r = i >> 5, c8 = (i & 31) << 3;
            *reinterpret_cast<uint4*>(&B2q[r * 264 + c8]) =
                *reinterpret_cast<const uint4*>(Wt2 + (size_t)(c2 * 32 + r) * 256 + c8);
        }
        __syncthreads();

        floatx4 acc2[2];
        acc2[0] = {0.f, 0.f, 0.f, 0.f};
        acc2[1] = {0.f, 0.f, 0.f, 0.f};
#pragma unroll
        for (int ks = 0; ks < 8; ++ks) {
            const int kb = ks * 32 + quad * 8;
            short8 t0 = *reinterpret_cast<const short8*>(&T[((w & 1) * 32 + qm) * 264 + kb]);
            short8 t1 = *reinterpret_cast<const short8*>(&T[((w & 1) * 32 + 16 + qm) * 264 + kb]);
            short8 bb = *reinterpret_cast<const short8*>(&B2q[((w >> 1) * 16 + qm) * 264 + kb]);
            acc2[0] = __builtin_amdgcn_mfma_f32_16x16x32_bf16(t0, bb, acc2[0], 0, 0, 0);
            acc2[1] = __builtin_amdgcn_mfma_f32_16x16x32_bf16(t1, bb, acc2[1], 0, 0, 0);
        }

        const int ncol = c2 * 32 + (w >> 1) * 16 + qm;   // global h col
        const float bj = b2[ncol];
        if (!FUSE) {
#pragma unroll
            for (int mt2 = 0; mt2 < 2; ++mt2)
#pragma unroll
                for (int r = 0; r < 4; ++r) {
                    int row = m0 + (w & 1) * 32 + mt2 * 16 + quad * 4 + r;
                    if (row < M)
                        Y[(size_t)row * 128 + ncol] = f2b(fmaxf(acc2[mt2][r] + bj, 0.f));
                }
            __syncthreads();
        } else {
            const int lcol = (w >> 1) * 16 + qm;
#pragma unroll
            for (int mt2 = 0; mt2 < 2; ++mt2)
#pragma unroll
                for (int r = 0; r < 4; ++r)
                    Hc[((w & 1) * 32 + mt2 * 16 + quad * 4 + r) * 40 + lcol] =
                        f2b(fmaxf(acc2[mt2][r] + bj, 0.f));
            __syncthreads();
            // classifier partial: out += h[:, c2*32:+32] @ Wfct[:, c2*32:+32]^T
            short8 hf = *reinterpret_cast<const short8*>(&Hc[(w * 16 + qm) * 40 + quad * 8]);
#pragma unroll
            for (int nt = 0; nt < 3; ++nt) {
                short8 bf = *reinterpret_cast<const short8*>(
                    Wfct + (nt * 16 + qm) * 128 + c2 * 32 + quad * 8);
                cacc[nt] = __builtin_amdgcn_mfma_f32_16x16x32_bf16(hf, bf, cacc[nt], 0, 0, 0);
            }
            __syncthreads();
        }
    }

    if (FUSE) {
#pragma unroll
        for (int nt = 0; nt < 3; ++nt) {
            int col = nt * 16 + qm;
            if (col < 40) {
                const float bj = bfc[col];
#pragma unroll
                for (int r = 0; r < 4; ++r) {
                    int row = m0 + w * 16 + quad * 4 + r;
                    if (row < M) out[(size_t)row * 40 + col] = cacc[nt][r] + bj;
                }
            }
        }
    }
}

// ---------------------------------------------------------------------------
extern "C" void kernel_launch(void* const* d_in, const int* in_sizes, int n_in,
                              void* d_out, int out_size, void* d_ws, size_t ws_size,
                              hipStream_t stream) {
    const float* x   = (const float*)d_in[0];
    const int*   ei  = (const int*)d_in[1];
    const float* W11 = (const float*)d_in[2];
    const float* b11 = (const float*)d_in[3];
    const float* W12 = (const float*)d_in[4];
    const float* b12 = (const float*)d_in[5];
    const float* W21 = (const float*)d_in[6];
    const float* b21 = (const float*)d_in[7];
    const float* W22 = (const float*)d_in[8];
    const float* b22 = (const float*)d_in[9];
    const float* Wfc = (const float*)d_in[10];
    const float* bfc = (const float*)d_in[11];
    float* out = (float*)d_out;

    const int* srcv = ei;
    const int* dstv = ei + N_EDGES;

    unsigned short* agg  = (unsigned short*)d_ws;               // 50000*128 bf16
    unsigned short* h    = agg + (size_t)N_NODES * 128;         // 50000*128 bf16
    unsigned short* xb   = h   + (size_t)N_NODES * 128;         // 50000*128 bf16
    unsigned short* Wt11 = xb  + (size_t)N_NODES * 128;
    unsigned short* Wt12 = Wt11 + 256 * 128;
    unsigned short* Wt21 = Wt12 + 256 * 128;
    unsigned short* Wt22 = Wt21 + 256 * 128;
    unsigned short* Wfct = Wt22 + 256 * 128;                    // 48*128
    int* cnt     = (int*)(Wfct + 48 * 128);                     // 98*391 (pad 38400)
    int* row_ptr = cnt + 38400;                                 // 98*513 (pad 50304)
    int* e_src   = row_ptr + 50304;                             // 98*12288
    int* tmp     = e_src + (size_t)NBUCK * CAPB;                // 391*98*64 = 2.45M

    // ---- prep (weights + Wfc + x->bf16) + edge scatter, one kernel ----
    prep_scatter<<<NSB + 3661, 256, 0, stream>>>(
        x, W11, W12, W21, W22, Wfc, srcv, dstv,
        xb, Wt11, Wt12, Wt21, Wt22, Wfct, cnt, tmp);

    // ---- per-bucket CSR sort (independent buckets, no global scan) ----
    bucket_sort_ex<<<NBUCK, 256, 0, stream>>>(cnt, tmp, e_src, row_ptr);

    const int agg_blocks = N_NODES * 64 / 256;        // 12500, one wave per node
    const int mlp_blocks = (N_NODES + 63) / 64;       // 782

    // ---- layer 1 ----
    agg_bf16q<<<agg_blocks, 256, 0, stream>>>(xb, row_ptr, e_src, agg);
    mlp_fused<false><<<mlp_blocks, 256, 0, stream>>>(
        agg, Wt11, b11, Wt12, b12, h, nullptr, nullptr, nullptr, N_NODES);
    // ---- layer 2 + classifier ----
    agg_bf16q<<<agg_blocks, 256, 0, stream>>>(h, row_ptr, e_src, agg);
    mlp_fused<true><<<mlp_blocks, 256, 0, stream>>>(
        agg, Wt21, b21, Wt22, b22, nullptr, Wfct, bfc, out, N_NODES);
}